// Round 1
// baseline (1251.628 us; speedup 1.0000x reference)
//
#include <hip/hip_runtime.h>
#include <hip/hip_bf16.h>

// Problem constants (from reference setup_inputs):
//   original: (N=4096, T=256, C=10) f32, generated: (B=1024, T=256, C=10) f32
//   sample_idx: (B=1024,) indices into N
//   depth 4, C=10 -> levels 10 + 100 + 1000 + 10000 = 11110
#define T_LEN 256
#define C_DIM 10
#define NSTEP 255            // T-1 increments
#define BSZ 1024             // generated batch / sample count
#define D1 10
#define D2 100
#define D3 1000
#define D4 10000
#define DTOT 11110
#define PATH_ELEMS (T_LEN * C_DIM)   // 2560
#define DX_ELEMS (NSTEP * C_DIM)     // 2550
#define MAX_REP 8

// One block per path. Horner-factored Chen step:
//   A2 = S2 + (S1 + v/4) (x) v/3
//   A3 = S3 + A2 (x) v/2
//   S4' = S4 + A3 (x) v            (S4 in registers, 40 floats/thread)
//   B2 = S2 + (S1 + v/3) (x) v/2
//   S3' = S3 + B2 (x) v
//   S2' = S2 + (S1 + v/2) (x) v
//   S1' = S1 + v
// Starting from S=0, 255 steps gives the full signature (step 1 == exp(dx0)).
__global__ __launch_bounds__(256) void sig_accum_kernel(
    const float* __restrict__ original,
    const float* __restrict__ generated,
    const int* __restrict__ sample_idx,
    float* __restrict__ ws, int nrep)
{
    const int tid = threadIdx.x;
    const int b = blockIdx.x;

    __shared__ float s_dx[DX_ELEMS];   // 10200 B
    __shared__ float sS1[D1];
    __shared__ float sS2[D2];
    __shared__ float sS3[D3];          // 4440 B state
    __shared__ float sA2[D2];
    __shared__ float sB2[D2];
    __shared__ float sA3[D3];          // 4800 B temps; total ~19.4 KB

    const float* path;
    float sign;
    if (b < BSZ) {
        int idx = sample_idx[b];
        path = original + (size_t)idx * PATH_ELEMS;
        sign = 1.0f;
    } else {
        path = generated + (size_t)(b - BSZ) * PATH_ELEMS;
        sign = -1.0f;
    }

    // Precompute increments dx[t][c] = x[t+1][c] - x[t][c] into LDS.
    for (int idx = tid; idx < DX_ELEMS; idx += 256)
        s_dx[idx] = path[idx + C_DIM] - path[idx];

    // Zero state.
    if (tid < D1) sS1[tid] = 0.0f;
    if (tid < D2) sS2[tid] = 0.0f;
    #pragma unroll
    for (int r = 0; r < 4; ++r) {
        int m = tid + r * 256;
        if (m < D3) sS3[m] = 0.0f;
    }
    float acc[4][10];
    #pragma unroll
    for (int r = 0; r < 4; ++r)
        #pragma unroll
        for (int l = 0; l < 10; ++l) acc[r][l] = 0.0f;

    const int i_of = tid / 10;   // valid when tid < 100
    const int j_of = tid % 10;

    __syncthreads();

    for (int t = 0; t < NSTEP; ++t) {
        const float* v = &s_dx[t * C_DIM];

        // ---- Phase A: level-2 temporaries + S2 update (threads 0..99) ----
        if (tid < D2) {
            float s1 = sS1[i_of];
            float vi = v[i_of];
            float vj = v[j_of];
            float s2 = sS2[tid];
            sA2[tid] = s2 + (s1 + vi * 0.25f)        * (vj * (1.0f / 3.0f));
            sB2[tid] = s2 + (s1 + vi * (1.0f/3.0f))  * (vj * 0.5f);
            sS2[tid] = s2 + (s1 + vi * 0.5f)         * vj;
        }
        __syncthreads();

        // ---- Phase B: A3 + S3 update (1000 elems), S1 update ----
        if (tid < D1) sS1[tid] += v[tid];
        #pragma unroll
        for (int r = 0; r < 4; ++r) {
            int m = tid + r * 256;
            if (m < D3) {
                int ij = m / 10;
                int k  = m % 10;
                float s3 = sS3[m];
                float vk = v[k];
                sA3[m] = s3 + sA2[ij] * (vk * 0.5f);
                sS3[m] = s3 + sB2[ij] * vk;
            }
        }
        __syncthreads();

        // ---- Phase C: S4 += A3 (x) v, in registers ----
        float vr[10];
        #pragma unroll
        for (int l = 0; l < 10; ++l) vr[l] = v[l];
        #pragma unroll
        for (int r = 0; r < 4; ++r) {
            int m = tid + r * 256;
            if (m < D3) {
                float a3 = sA3[m];
                #pragma unroll
                for (int l = 0; l < 10; ++l)
                    acc[r][l] += a3 * vr[l];
            }
        }
        // No sync needed: next Phase A touches only S1/S2/A2/B2/dx, and the
        // next write to A3 (Phase B) is separated by Phase A's barrier.
    }

    // ---- Epilogue: signed atomic accumulation into replica nrep buckets ----
    float* base = ws + (size_t)(b % nrep) * DTOT;
    if (tid < D1)  atomicAdd(&base[tid], sign * sS1[tid]);
    if (tid < D2)  atomicAdd(&base[D1 + tid], sign * sS2[tid]);
    #pragma unroll
    for (int r = 0; r < 4; ++r) {
        int m = tid + r * 256;
        if (m < D3) {
            atomicAdd(&base[D1 + D2 + m], sign * sS3[m]);
            #pragma unroll
            for (int l = 0; l < 10; ++l)
                atomicAdd(&base[D1 + D2 + D3 + m * 10 + l], sign * acc[r][l]);
        }
    }
}

// Sum replicas, sum of squares, norm / B.
__global__ __launch_bounds__(256) void sig_finalize_kernel(
    const float* __restrict__ ws, int nrep, float* __restrict__ out)
{
    float sumsq = 0.0f;
    for (int idx = threadIdx.x; idx < DTOT; idx += 256) {
        float s = 0.0f;
        for (int r = 0; r < nrep; ++r)
            s += ws[(size_t)r * DTOT + idx];
        sumsq += s * s;
    }
    // block reduction: wave shuffles then LDS
    for (int off = 32; off > 0; off >>= 1)
        sumsq += __shfl_down(sumsq, off, 64);
    __shared__ float red[4];
    if ((threadIdx.x & 63) == 0) red[threadIdx.x >> 6] = sumsq;
    __syncthreads();
    if (threadIdx.x == 0) {
        float s = red[0] + red[1] + red[2] + red[3];
        out[0] = sqrtf(s) * (1.0f / (float)BSZ);
    }
}

extern "C" void kernel_launch(void* const* d_in, const int* in_sizes, int n_in,
                              void* d_out, int out_size, void* d_ws, size_t ws_size,
                              hipStream_t stream) {
    const float* original  = (const float*)d_in[0];
    const float* generated = (const float*)d_in[1];
    const int*   sample_idx = (const int*)d_in[2];
    float* out = (float*)d_out;
    float* ws  = (float*)d_ws;

    int nrep = 1;
    if (ws_size >= (size_t)MAX_REP * DTOT * sizeof(float)) nrep = MAX_REP;

    // Zero the accumulator replicas (d_ws is poisoned 0xAA before each call).
    hipMemsetAsync(d_ws, 0, (size_t)nrep * DTOT * sizeof(float), stream);

    sig_accum_kernel<<<2 * BSZ, 256, 0, stream>>>(original, generated, sample_idx, ws, nrep);
    sig_finalize_kernel<<<1, 256, 0, stream>>>(ws, nrep, out);
}

// Round 2
// 770.620 us; speedup vs baseline: 1.6242x; 1.6242x over previous
//
#include <hip/hip_runtime.h>

// SigWassersteinMetric: depth-4 path signature, C=10, T=256.
//   original: (4096, 256, 10) f32; generated: (1024, 256, 10) f32; sample_idx: (1024,)
// Only the 1024 sampled original paths + 1024 generated paths are computed (2048 blocks).
// Horner-factored Chen step (verified exact vs reference in round 1):
//   A2 = S2 + (S1 + v/4) (x) v/3
//   B2 = S2 + (S1 + v/3) (x) v/2
//   A3 = S3 + A2 (x) v/2      (kept in registers, transposed layout)
//   S4' = S4 + A3 (x) v        (registers)
//   S3' = S3 + B2 (x) v        (registers)
//   S2' = S2 + (S1 + v/2) (x) v   (1 reg/thread, tid<100)
//   S1' = S1 + v                   (LDS, 10 floats)
#define T_LEN 256
#define C_DIM 10
#define NSTEP 255
#define BSZ   1024
#define NBLK  2048
#define D1 10
#define D2 100
#define D3 1000
#define DTOT 11110
#define PATH_ELEMS (T_LEN * C_DIM)   // 2560
#define DX_ELEMS (NSTEP * C_DIM)     // 2550
#define DXROW 12                     // padded dx row stride (48 B, 16B-aligned)

// Transposed level-3/4 row index: m' = k*100 + ij  (ij in [0,100), k in [0,10)).
// Thread t (<125) owns rows m' = {4t..4t+3, 500+4t..500+4t+3}: same ij, k and k+5.
// Original flat index of level-3 element (ij,k) = ij*10 + k; level-4 adds *10 + l.
__global__ __launch_bounds__(128, 4) void sig_accum_kernel(
    const float* __restrict__ original,
    const float* __restrict__ generated,
    const int* __restrict__ sample_idx,
    float* __restrict__ ws, int nrep, int store_mode)
{
    const int tid = threadIdx.x;
    const int b   = blockIdx.x;

    __shared__ float s_dx[NSTEP * DXROW];  // 12240 B
    __shared__ float sA2[D2];              // 400 B
    __shared__ float sB2[D2];              // 400 B
    __shared__ float sS1[D1];              // 40 B   -> total ~13.1 KB

    const float* path;
    float sign;
    if (b < BSZ) { path = original + (size_t)sample_idx[b] * PATH_ELEMS; sign = 1.0f; }
    else         { path = generated + (size_t)(b - BSZ) * PATH_ELEMS;    sign = -1.0f; }

    // Stage increments into padded LDS rows.
    for (int idx = tid; idx < DX_ELEMS; idx += 128) {
        int t = idx / C_DIM, c = idx - t * C_DIM;
        s_dx[t * DXROW + c] = path[idx + C_DIM] - path[idx];
    }

    // Loop-invariant per-thread indices.
    const int i_idx = tid / C_DIM;            // valid tid<100
    const int j_idx = tid - i_idx * C_DIM;
    const int m0  = 4 * tid;                  // valid tid<125
    const int k0  = m0 / 100;
    const int ij0 = m0 - k0 * 100;

    float s1own = 0.0f;                       // S1[tid], tid<10
    float s2own = 0.0f;                       // S2[tid], tid<100
    float s3[2][4];
    float acc[2][4][10];
    #pragma unroll
    for (int ch = 0; ch < 2; ++ch)
        #pragma unroll
        for (int r = 0; r < 4; ++r) {
            s3[ch][r] = 0.0f;
            #pragma unroll
            for (int l = 0; l < 10; ++l) acc[ch][r][l] = 0.0f;
        }
    if (tid < D1) sS1[tid] = 0.0f;
    __syncthreads();

    #pragma unroll 1
    for (int t = 0; t < NSTEP; ++t) {
        const int toff = t * DXROW;

        // Uniform v -> registers (3 broadcast vector LDS reads per wave).
        const float4 va = *(const float4*)&s_dx[toff];
        const float4 vb = *(const float4*)&s_dx[toff + 4];
        const float2 vc = *(const float2*)&s_dx[toff + 8];
        const float vv[10] = {va.x, va.y, va.z, va.w, vb.x, vb.y, vb.z, vb.w, vc.x, vc.y};

        // Phase A: level-2 temporaries (threads 0..99), S2 in register.
        if (tid < D2) {
            float s1 = sS1[i_idx];
            float vi = s_dx[toff + i_idx];
            float vj = s_dx[toff + j_idx];
            sA2[tid] = s2own + (s1 + vi * 0.25f)         * (vj * (1.0f / 3.0f));
            sB2[tid] = s2own + (s1 + vi * (1.0f / 3.0f)) * (vj * 0.5f);
            s2own    = s2own + (s1 + vi * 0.5f)          * vj;
        }
        __syncthreads();

        // S1 update for NEXT step (readers of old S1 are past the barrier).
        if (tid < D1) { s1own += s_dx[toff + tid]; sS1[tid] = s1own; }

        // Phase B+C fused, all in registers (threads 0..124).
        if (tid < 125) {
            const float4 A2c = *(const float4*)&sA2[ij0];   // ij0 % 4 == 0 -> aligned
            const float4 B2c = *(const float4*)&sB2[ij0];
            const float vk0 = s_dx[toff + k0];
            const float vk1 = s_dx[toff + k0 + 5];
            const float a2r[4] = {A2c.x, A2c.y, A2c.z, A2c.w};
            const float b2r[4] = {B2c.x, B2c.y, B2c.z, B2c.w};
            #pragma unroll
            for (int r = 0; r < 4; ++r) {
                float a3 = s3[0][r] + a2r[r] * (vk0 * 0.5f);
                s3[0][r] += b2r[r] * vk0;
                #pragma unroll
                for (int l = 0; l < 10; ++l) acc[0][r][l] += a3 * vv[l];
            }
            #pragma unroll
            for (int r = 0; r < 4; ++r) {
                float a3 = s3[1][r] + a2r[r] * (vk1 * 0.5f);
                s3[1][r] += b2r[r] * vk1;
                #pragma unroll
                for (int l = 0; l < 10; ++l) acc[1][r][l] += a3 * vv[l];
            }
        }
        __syncthreads();
    }

    // ---- Epilogue ----
    if (store_mode) {
        // Non-atomic: each block writes its signed signature row.
        float* row = ws + (size_t)b * DTOT;
        if (tid < D1) row[tid] = sign * s1own;
        if (tid < D2) row[D1 + tid] = sign * s2own;
        if (tid < 125) {
            #pragma unroll
            for (int ch = 0; ch < 2; ++ch) {
                const int kk = k0 + 5 * ch;
                #pragma unroll
                for (int r = 0; r < 4; ++r) {
                    const int idx3 = (ij0 + r) * 10 + kk;
                    row[D1 + D2 + idx3] = sign * s3[ch][r];
                    float* p4 = row + D1 + D2 + D3 + (size_t)idx3 * 10;
                    #pragma unroll
                    for (int l = 0; l < 10; l += 2) {  // 8B-aligned float2 stores
                        *(float2*)&p4[l] = make_float2(sign * acc[ch][r][l],
                                                       sign * acc[ch][r][l + 1]);
                    }
                }
            }
        }
    } else {
        // Atomic fallback: nrep XCD-aligned replicas (rep % 8 tracks blockIdx % 8).
        float* base = ws + (size_t)(b % nrep) * DTOT;
        if (tid < D1) atomicAdd(&base[tid], sign * s1own);
        if (tid < D2) atomicAdd(&base[D1 + tid], sign * s2own);
        if (tid < 125) {
            #pragma unroll
            for (int ch = 0; ch < 2; ++ch) {
                const int kk = k0 + 5 * ch;
                #pragma unroll
                for (int r = 0; r < 4; ++r) {
                    const int idx3 = (ij0 + r) * 10 + kk;
                    atomicAdd(&base[D1 + D2 + idx3], sign * s3[ch][r]);
                    #pragma unroll
                    for (int l = 0; l < 10; ++l)
                        atomicAdd(&base[D1 + D2 + D3 + idx3 * 10 + l], sign * acc[ch][r][l]);
                }
            }
        }
    }
}

// Sum nrows rows of DTOT, square, block-reduce, atomic-accumulate sumsq.
__global__ __launch_bounds__(256) void sig_reduce_kernel(
    const float* __restrict__ ws, int nrows, float* __restrict__ sumsq)
{
    const int d = blockIdx.x * 256 + threadIdx.x;
    float s = 0.0f;
    if (d < DTOT) {
        for (int r = 0; r < nrows; ++r) s += ws[(size_t)r * DTOT + d];
        s = s * s;
    }
    for (int off = 32; off > 0; off >>= 1) s += __shfl_down(s, off, 64);
    __shared__ float red[4];
    if ((threadIdx.x & 63) == 0) red[threadIdx.x >> 6] = s;
    __syncthreads();
    if (threadIdx.x == 0) atomicAdd(sumsq, red[0] + red[1] + red[2] + red[3]);
}

__global__ void sig_norm_kernel(const float* __restrict__ sumsq, float* __restrict__ out)
{
    if (threadIdx.x == 0) out[0] = sqrtf(sumsq[0]) * (1.0f / (float)BSZ);
}

extern "C" void kernel_launch(void* const* d_in, const int* in_sizes, int n_in,
                              void* d_out, int out_size, void* d_ws, size_t ws_size,
                              hipStream_t stream) {
    const float* original   = (const float*)d_in[0];
    const float* generated  = (const float*)d_in[1];
    const int*   sample_idx = (const int*)d_in[2];
    float* out = (float*)d_out;
    float* ws  = (float*)d_ws;

    int store_mode, nrep, nrows;
    if (ws_size >= ((size_t)NBLK * DTOT + 1) * sizeof(float)) {        // ~91 MB
        store_mode = 1; nrep = 1; nrows = NBLK;
    } else if (ws_size >= ((size_t)64 * DTOT + 1) * sizeof(float)) {   // ~2.8 MB
        store_mode = 0; nrep = 64; nrows = 64;
    } else if (ws_size >= ((size_t)8 * DTOT + 1) * sizeof(float)) {    // ~356 KB
        store_mode = 0; nrep = 8; nrows = 8;
    } else {
        store_mode = 0; nrep = 1; nrows = 1;
    }

    float* sumsq = ws + (size_t)nrows * DTOT;
    if (store_mode) {
        hipMemsetAsync(sumsq, 0, sizeof(float), stream);
    } else {
        hipMemsetAsync(ws, 0, ((size_t)nrep * DTOT + 1) * sizeof(float), stream);
    }

    sig_accum_kernel<<<NBLK, 128, 0, stream>>>(original, generated, sample_idx,
                                               ws, nrep, store_mode);
    sig_reduce_kernel<<<(DTOT + 255) / 256, 256, 0, stream>>>(ws, nrows, sumsq);
    sig_norm_kernel<<<1, 64, 0, stream>>>(sumsq, out);
}

// Round 4
// 368.335 us; speedup vs baseline: 3.3981x; 2.0922x over previous
//
#include <hip/hip_runtime.h>

// SigWassersteinMetric: depth-4 path signature, C=10, T=256.
//   original: (4096, 256, 10) f32; generated: (1024, 256, 10) f32; sample_idx: (1024,)
// Only the 1024 sampled original paths + 1024 generated paths are computed (2048 blocks).
// Horner-factored Chen step (verified exact vs reference in rounds 1-2):
//   A2 = S2 + (S1 + v/4) (x) v/3
//   B2 = S2 + (S1 + v/3) (x) v/2
//   A3 = S3 + A2 (x) v/2      (registers, transposed layout)
//   S4' = S4 + A3 (x) v        (registers)
//   S3' = S3 + B2 (x) v        (registers)
//   S2' = S2 + (S1 + v/2) (x) v   (1 reg/thread, tid<100)
//   S1' = S1 + v                   (LDS, double-buffered)
#define T_LEN 256
#define C_DIM 10
#define NSTEP 255
#define BSZ   1024
#define NBLK  2048
#define D1 10
#define D2 100
#define D3 1000
#define DTOT 11110
#define PATH_ELEMS (T_LEN * C_DIM)   // 2560
#define DX_ELEMS (NSTEP * C_DIM)     // 2550
#define DXROW 12                     // padded dx row stride (48 B, 16B-aligned)

// Transposed level-3/4 row index: m' = k*100 + ij. Thread t (<125) owns
// m' = {4t..4t+3, 500+4t..500+4t+3}: same ij block, k and k+5.
// Single barrier per step: Phase A(t) writes buf t&1 of {A2,B2} and buf (t+1)&1
// of S1; barrier; Phase B/C(t) reads buf t&1. Phase A(t+1) writes the OTHER
// A2/B2 buffer (no conflict with lagging B/C readers) and reads S1[(t+1)&1]
// which was written before the t-barrier. All cross-wave pairs barrier-separated.
// ROUND-3 BUG (fixed): S1 update must use s_dx[toff + tid] — for tid<10,
// i_idx = tid/10 == 0, NOT tid. Keep the S1 update in its own branch.
__global__ __launch_bounds__(128, 4) void sig_accum_kernel(
    const float* __restrict__ original,
    const float* __restrict__ generated,
    const int* __restrict__ sample_idx,
    float* __restrict__ ws, int nrep, int store_mode)
{
    const int tid = threadIdx.x;
    const int b   = blockIdx.x;

    __shared__ float s_dx[NSTEP * DXROW];  // 12240 B
    __shared__ float sA2[2][D2];           // 800 B
    __shared__ float sB2[2][D2];           // 800 B
    __shared__ float sS1[2][D1];           // 80 B   -> total ~13.9 KB

    const float* path;
    float sign;
    if (b < BSZ) { path = original + (size_t)sample_idx[b] * PATH_ELEMS; sign = 1.0f; }
    else         { path = generated + (size_t)(b - BSZ) * PATH_ELEMS;    sign = -1.0f; }

    // Stage increments into padded LDS rows.
    for (int idx = tid; idx < DX_ELEMS; idx += 128) {
        int t = idx / C_DIM, c = idx - t * C_DIM;
        s_dx[t * DXROW + c] = path[idx + C_DIM] - path[idx];
    }

    const int i_idx = tid / C_DIM;            // valid tid<100
    const int j_idx = tid - i_idx * C_DIM;
    const int m0  = 4 * tid;                  // valid tid<125
    const int k0  = m0 / 100;
    const int ij0 = m0 - k0 * 100;

    float s1own = 0.0f;                       // S1[tid], tid<10
    float s2own = 0.0f;                       // S2[tid], tid<100
    float s3[2][4];
    float acc[2][4][10];
    #pragma unroll
    for (int ch = 0; ch < 2; ++ch)
        #pragma unroll
        for (int r = 0; r < 4; ++r) {
            s3[ch][r] = 0.0f;
            #pragma unroll
            for (int l = 0; l < 10; ++l) acc[ch][r][l] = 0.0f;
        }
    if (tid < D1) sS1[0][tid] = 0.0f;
    __syncthreads();

    #pragma unroll 1
    for (int t = 0; t < NSTEP; ++t) {
        const int toff = t * DXROW;
        const int buf  = t & 1;

        // Phase A: level-2 temporaries (threads 0..99).
        if (tid < D2) {
            float s1 = sS1[buf][i_idx];
            float vi = s_dx[toff + i_idx];
            float vj = s_dx[toff + j_idx];
            sA2[buf][tid] = s2own + (s1 + vi * 0.25f)         * (vj * (1.0f / 3.0f));
            sB2[buf][tid] = s2own + (s1 + vi * (1.0f / 3.0f)) * (vj * 0.5f);
            s2own         = s2own + (s1 + vi * 0.5f)          * vj;
        }
        // S1 for next step: own element is s_dx[toff + tid] (NOT i_idx!).
        if (tid < D1) { s1own += s_dx[toff + tid]; sS1[buf ^ 1][tid] = s1own; }
        __syncthreads();

        // Phase B/C fused, all in registers (threads 0..124).
        if (tid < 125) {
            const float4 va = *(const float4*)&s_dx[toff];
            const float4 vb = *(const float4*)&s_dx[toff + 4];
            const float2 vc = *(const float2*)&s_dx[toff + 8];
            const float vv[10] = {va.x, va.y, va.z, va.w, vb.x, vb.y, vb.z, vb.w, vc.x, vc.y};
            const float4 A2c = *(const float4*)&sA2[buf][ij0];   // ij0 % 4 == 0 -> aligned
            const float4 B2c = *(const float4*)&sB2[buf][ij0];
            const float vk0 = vv[k0];
            const float vk1 = vv[k0 + 5];
            const float a2r[4] = {A2c.x, A2c.y, A2c.z, A2c.w};
            const float b2r[4] = {B2c.x, B2c.y, B2c.z, B2c.w};
            #pragma unroll
            for (int r = 0; r < 4; ++r) {
                float a3 = s3[0][r] + a2r[r] * (vk0 * 0.5f);
                s3[0][r] += b2r[r] * vk0;
                #pragma unroll
                for (int l = 0; l < 10; ++l) acc[0][r][l] += a3 * vv[l];
            }
            #pragma unroll
            for (int r = 0; r < 4; ++r) {
                float a3 = s3[1][r] + a2r[r] * (vk1 * 0.5f);
                s3[1][r] += b2r[r] * vk1;
                #pragma unroll
                for (int l = 0; l < 10; ++l) acc[1][r][l] += a3 * vv[l];
            }
        }
        // single barrier per step (see header comment for the hazard analysis)
    }

    // ---- Epilogue ----
    if (store_mode) {
        float* row = ws + (size_t)b * DTOT;
        if (tid < D1) row[tid] = sign * s1own;
        if (tid < D2) row[D1 + tid] = sign * s2own;
        if (tid < 125) {
            #pragma unroll
            for (int ch = 0; ch < 2; ++ch) {
                const int kk = k0 + 5 * ch;
                #pragma unroll
                for (int r = 0; r < 4; ++r) {
                    const int idx3 = (ij0 + r) * 10 + kk;
                    row[D1 + D2 + idx3] = sign * s3[ch][r];
                    float* p4 = row + D1 + D2 + D3 + (size_t)idx3 * 10;
                    #pragma unroll
                    for (int l = 0; l < 10; l += 2) {
                        *(float2*)&p4[l] = make_float2(sign * acc[ch][r][l],
                                                       sign * acc[ch][r][l + 1]);
                    }
                }
            }
        }
    } else {
        float* base = ws + (size_t)(b % nrep) * DTOT;
        if (tid < D1) atomicAdd(&base[tid], sign * s1own);
        if (tid < D2) atomicAdd(&base[D1 + tid], sign * s2own);
        if (tid < 125) {
            #pragma unroll
            for (int ch = 0; ch < 2; ++ch) {
                const int kk = k0 + 5 * ch;
                #pragma unroll
                for (int r = 0; r < 4; ++r) {
                    const int idx3 = (ij0 + r) * 10 + kk;
                    atomicAdd(&base[D1 + D2 + idx3], sign * s3[ch][r]);
                    #pragma unroll
                    for (int l = 0; l < 10; ++l)
                        atomicAdd(&base[D1 + D2 + D3 + idx3 * 10 + l], sign * acc[ch][r][l]);
                }
            }
        }
    }
}

// Stage 1: each block sums 32 rows for a 256-wide d-tile (coalesced) and
// atomically accumulates into accvec[DTOT]. Grid: (44, 64).
__global__ __launch_bounds__(256) void sig_sum_kernel(
    const float* __restrict__ ws, float* __restrict__ accvec)
{
    const int d = blockIdx.x * 256 + threadIdx.x;
    if (d >= DTOT) return;
    const float* p = ws + (size_t)(blockIdx.y * 32) * DTOT + d;
    float s = 0.0f;
    #pragma unroll
    for (int r = 0; r < 32; ++r) s += p[(size_t)r * DTOT];
    atomicAdd(&accvec[d], s);
}

// Stage 2: sum of squares of accvec -> atomicAdd(sumsq). Grid: 44 blocks.
__global__ __launch_bounds__(256) void sig_sumsq_kernel(
    const float* __restrict__ accvec, float* __restrict__ sumsq)
{
    const int d = blockIdx.x * 256 + threadIdx.x;
    float s = 0.0f;
    if (d < DTOT) { float v = accvec[d]; s = v * v; }
    for (int off = 32; off > 0; off >>= 1) s += __shfl_down(s, off, 64);
    __shared__ float red[4];
    if ((threadIdx.x & 63) == 0) red[threadIdx.x >> 6] = s;
    __syncthreads();
    if (threadIdx.x == 0) atomicAdd(sumsq, red[0] + red[1] + red[2] + red[3]);
}

// Fallback reduce for small-ws atomic-replica modes.
__global__ __launch_bounds__(256) void sig_reduce_kernel(
    const float* __restrict__ ws, int nrows, float* __restrict__ sumsq)
{
    const int d = blockIdx.x * 256 + threadIdx.x;
    float s = 0.0f;
    if (d < DTOT) {
        for (int r = 0; r < nrows; ++r) s += ws[(size_t)r * DTOT + d];
        s = s * s;
    }
    for (int off = 32; off > 0; off >>= 1) s += __shfl_down(s, off, 64);
    __shared__ float red[4];
    if ((threadIdx.x & 63) == 0) red[threadIdx.x >> 6] = s;
    __syncthreads();
    if (threadIdx.x == 0) atomicAdd(sumsq, red[0] + red[1] + red[2] + red[3]);
}

__global__ void sig_norm_kernel(const float* __restrict__ sumsq, float* __restrict__ out)
{
    if (threadIdx.x == 0) out[0] = sqrtf(sumsq[0]) * (1.0f / (float)BSZ);
}

extern "C" void kernel_launch(void* const* d_in, const int* in_sizes, int n_in,
                              void* d_out, int out_size, void* d_ws, size_t ws_size,
                              hipStream_t stream) {
    const float* original   = (const float*)d_in[0];
    const float* generated  = (const float*)d_in[1];
    const int*   sample_idx = (const int*)d_in[2];
    float* out = (float*)d_out;
    float* ws  = (float*)d_ws;

    // Preferred layout: rows [0, NBLK*DTOT), accvec [NBLK*DTOT, +DTOT), sumsq [+1]
    const size_t need_store = ((size_t)(NBLK + 1) * DTOT + 1) * sizeof(float);

    if (ws_size >= need_store) {
        float* accvec = ws + (size_t)NBLK * DTOT;
        float* sumsq  = accvec + DTOT;
        hipMemsetAsync(accvec, 0, (DTOT + 1) * sizeof(float), stream);
        sig_accum_kernel<<<NBLK, 128, 0, stream>>>(original, generated, sample_idx,
                                                   ws, 1, 1);
        dim3 g1((DTOT + 255) / 256, 64);
        sig_sum_kernel<<<g1, 256, 0, stream>>>(ws, accvec);
        sig_sumsq_kernel<<<(DTOT + 255) / 256, 256, 0, stream>>>(accvec, sumsq);
        sig_norm_kernel<<<1, 64, 0, stream>>>(sumsq, out);
    } else {
        int nrep = 1;
        if (ws_size >= ((size_t)64 * DTOT + 1) * sizeof(float)) nrep = 64;
        else if (ws_size >= ((size_t)8 * DTOT + 1) * sizeof(float)) nrep = 8;
        float* sumsq = ws + (size_t)nrep * DTOT;
        hipMemsetAsync(ws, 0, ((size_t)nrep * DTOT + 1) * sizeof(float), stream);
        sig_accum_kernel<<<NBLK, 128, 0, stream>>>(original, generated, sample_idx,
                                                   ws, nrep, 0);
        sig_reduce_kernel<<<(DTOT + 255) / 256, 256, 0, stream>>>(ws, nrep, sumsq);
        sig_norm_kernel<<<1, 64, 0, stream>>>(sumsq, out);
    }
}

// Round 5
// 309.135 us; speedup vs baseline: 4.0488x; 1.1915x over previous
//
#include <hip/hip_runtime.h>

// SigWassersteinMetric: depth-4 path signature, C=10, T=256.
//   original: (4096, 256, 10) f32; generated: (1024, 256, 10) f32; sample_idx: (1024,)
// 2048 blocks (1024 sampled originals + 1024 generated), 128 threads each.
//
// Horner-factored Chen step (verified rounds 2/4):
//   A2 = S2 + (S1 + v/4) (x) v/3
//   B2 = S2 + (S1 + v/3) (x) v/2
//   A3 = S3 + A2 (x) v/2 ;  S4' = S4 + A3 (x) v ;  S3' = S3 + B2 (x) v
//   S2' = S2 + (S1 + v/2) (x) v ;  S1' = S1 + v
//
// ROUND-5 RESTRUCTURE: barrier-free main loop. Thread t (<125) owns rows
// m' = {4t..4t+3, 500+4t..500+4t+3} of the transposed (k*100+ij) level-3/4
// layout: 4 ij values (ij0..ij0+3, ij0 = 4t%100, multiple of 4) x 2 k values
// (k0, k0+5). It REPLICATES the S1/S2 evolution it needs in registers:
//   - s1a,s1b: running sums of dx[., ia], dx[., ib]  (ia = ij0/10, ib = (ij0+2)/10;
//     q0,q1 share ia; q2,q3 share ib — ij0 even => no decade crossing inside pairs)
//   - s2[4]: S2[ij0+q], updated from s1a/s1b + v reads
// All v operands are fixed-offset LDS reads from the read-only s_dx (padded
// rows of 12 floats): broadcast or <=5 distinct addrs/wave, distinct banks.
// j0 = ij0%10 and jc = (j0+2)%10 are EVEN => 8B-aligned float2 reads.
#define T_LEN 256
#define C_DIM 10
#define NSTEP 255
#define BSZ   1024
#define NBLK  2048
#define D1 10
#define D2 100
#define D3 1000
#define DTOT 11110
#define PATH_ELEMS (T_LEN * C_DIM)   // 2560
#define DX_ELEMS (NSTEP * C_DIM)     // 2550
#define DXROW 12                     // padded dx row stride (48 B, 16B-aligned)

__global__ __launch_bounds__(128, 4) void sig_accum_kernel(
    const float* __restrict__ original,
    const float* __restrict__ generated,
    const int* __restrict__ sample_idx,
    float* __restrict__ ws, int nrep, int store_mode)
{
    const int tid = threadIdx.x;
    const int b   = blockIdx.x;

    __shared__ float s_dx[NSTEP * DXROW];  // 12240 B (only LDS use)

    const float* path;
    float sign;
    if (b < BSZ) { path = original + (size_t)sample_idx[b] * PATH_ELEMS; sign = 1.0f; }
    else         { path = generated + (size_t)(b - BSZ) * PATH_ELEMS;    sign = -1.0f; }

    for (int idx = tid; idx < DX_ELEMS; idx += 128) {
        int t = idx / C_DIM, c = idx - t * C_DIM;
        s_dx[t * DXROW + c] = path[idx + C_DIM] - path[idx];
    }
    __syncthreads();   // the ONLY barrier

    const int m0  = 4 * tid;                 // valid tid<125
    const int k0  = m0 / 100;                // 0..4
    const int ij0 = m0 - k0 * 100;           // 0,4,...,96
    const int ia  = ij0 / 10;                // i for q0,q1
    const int ib  = (ij0 + 2) / 10;          // i for q2,q3
    const int j0  = ij0 - ia * 10;           // even
    const int jc  = (j0 + 2) % 10;           // even

    float s1own = 0.0f;                      // level-1 output (tid<10)
    float s1a = 0.0f, s1b = 0.0f;
    float s2[4] = {0.0f, 0.0f, 0.0f, 0.0f};
    float s3[8];
    float acc[8][10];                        // rows 0-3: k0; rows 4-7: k0+5
    #pragma unroll
    for (int r = 0; r < 8; ++r) {
        s3[r] = 0.0f;
        #pragma unroll
        for (int l = 0; l < 10; ++l) acc[r][l] = 0.0f;
    }

    if (tid < 125) {
        const float* vrow = s_dx;
        #pragma unroll 1
        for (int t = 0; t < NSTEP; ++t, vrow += DXROW) {
            // ---- LDS loads (read-only, fixed per-thread offsets) ----
            const float4 va = *(const float4*)(vrow);       // v0..v3
            const float4 vb = *(const float4*)(vrow + 4);   // v4..v7
            const float2 vc = *(const float2*)(vrow + 8);   // v8,v9
            const float2 vjA = *(const float2*)(vrow + j0); // vj q0,q1
            const float2 vjB = *(const float2*)(vrow + jc); // vj q2,q3
            const float via = vrow[ia];
            const float vib = vrow[ib];
            const float vk0 = vrow[k0];
            const float vk1 = vrow[k0 + 5];
            if (tid < D1) s1own += vrow[tid];

            // ---- replicated level-2 (4 ij values) ----
            const float t1a = s1a + via * 0.25f;
            const float t2a = s1a + via * (1.0f / 3.0f);
            const float t3a = s1a + via * 0.5f;
            const float t1b = s1b + vib * 0.25f;
            const float t2b = s1b + vib * (1.0f / 3.0f);
            const float t3b = s1b + vib * 0.5f;
            const float vj[4] = {vjA.x, vjA.y, vjB.x, vjB.y};
            float a2[4], b2[4];
            #pragma unroll
            for (int q = 0; q < 4; ++q) {
                const float t1 = (q < 2) ? t1a : t1b;
                const float t2 = (q < 2) ? t2a : t2b;
                const float t3 = (q < 2) ? t3a : t3b;
                a2[q] = s2[q] + t1 * (vj[q] * (1.0f / 3.0f));
                b2[q] = s2[q] + t2 * (vj[q] * 0.5f);
                s2[q] = s2[q] + t3 * vj[q];
            }
            s1a += via;
            s1b += vib;

            // ---- level-3/4, all registers ----
            const float vv[10] = {va.x, va.y, va.z, va.w,
                                  vb.x, vb.y, vb.z, vb.w, vc.x, vc.y};
            const float vk0h = vk0 * 0.5f;
            const float vk1h = vk1 * 0.5f;
            #pragma unroll
            for (int r = 0; r < 4; ++r) {
                const float a3 = s3[r] + a2[r] * vk0h;
                s3[r] += b2[r] * vk0;
                #pragma unroll
                for (int l = 0; l < 10; ++l) acc[r][l] += a3 * vv[l];
            }
            #pragma unroll
            for (int r = 0; r < 4; ++r) {
                const float a3 = s3[4 + r] + a2[r] * vk1h;
                s3[4 + r] += b2[r] * vk1;
                #pragma unroll
                for (int l = 0; l < 10; ++l) acc[4 + r][l] += a3 * vv[l];
            }
        }
    }

    // ---- Epilogue ----
    // S2[ij] replicas agree across k0 groups; threads 0..24 (ij0=4*tid) write them.
    if (store_mode) {
        float* orow = ws + (size_t)b * DTOT;
        if (tid < D1) orow[tid] = sign * s1own;
        if (tid < 25) {
            #pragma unroll
            for (int q = 0; q < 4; ++q) orow[D1 + ij0 + q] = sign * s2[q];
        }
        if (tid < 125) {
            #pragma unroll
            for (int ch = 0; ch < 2; ++ch) {
                const int kk = k0 + 5 * ch;
                #pragma unroll
                for (int r = 0; r < 4; ++r) {
                    const int idx3 = (ij0 + r) * 10 + kk;
                    orow[D1 + D2 + idx3] = sign * s3[ch * 4 + r];
                    float* p4 = orow + D1 + D2 + D3 + (size_t)idx3 * 10;
                    #pragma unroll
                    for (int l = 0; l < 10; l += 2)
                        *(float2*)&p4[l] = make_float2(sign * acc[ch * 4 + r][l],
                                                       sign * acc[ch * 4 + r][l + 1]);
                }
            }
        }
    } else {
        float* base = ws + (size_t)(b % nrep) * DTOT;
        if (tid < D1) atomicAdd(&base[tid], sign * s1own);
        if (tid < 25) {
            #pragma unroll
            for (int q = 0; q < 4; ++q) atomicAdd(&base[D1 + ij0 + q], sign * s2[q]);
        }
        if (tid < 125) {
            #pragma unroll
            for (int ch = 0; ch < 2; ++ch) {
                const int kk = k0 + 5 * ch;
                #pragma unroll
                for (int r = 0; r < 4; ++r) {
                    const int idx3 = (ij0 + r) * 10 + kk;
                    atomicAdd(&base[D1 + D2 + idx3], sign * s3[ch * 4 + r]);
                    #pragma unroll
                    for (int l = 0; l < 10; ++l)
                        atomicAdd(&base[D1 + D2 + D3 + idx3 * 10 + l],
                                  sign * acc[ch * 4 + r][l]);
                }
            }
        }
    }
}

// Stage 1: block sums 32 rows for a 512-float d-tile (float2 lanes, coalesced),
// atomically accumulates into accvec[DTOT]. Grid: (ceil(5555/256), 64).
__global__ __launch_bounds__(256) void sig_sum_kernel(
    const float* __restrict__ ws, float* __restrict__ accvec)
{
    const int d2 = blockIdx.x * 256 + threadIdx.x;   // float2 index, DTOT/2 = 5555
    if (d2 >= DTOT / 2) return;
    const float* p = ws + (size_t)(blockIdx.y * 32) * DTOT + 2 * d2;
    float sx = 0.0f, sy = 0.0f;
    #pragma unroll
    for (int r = 0; r < 32; ++r) {
        const float2 v = *(const float2*)(p + (size_t)r * DTOT);
        sx += v.x; sy += v.y;
    }
    atomicAdd(&accvec[2 * d2], sx);
    atomicAdd(&accvec[2 * d2 + 1], sy);
}

// Stage 2: sum of squares of accvec -> atomicAdd(sumsq).
__global__ __launch_bounds__(256) void sig_sumsq_kernel(
    const float* __restrict__ accvec, float* __restrict__ sumsq)
{
    const int d = blockIdx.x * 256 + threadIdx.x;
    float s = 0.0f;
    if (d < DTOT) { float v = accvec[d]; s = v * v; }
    for (int off = 32; off > 0; off >>= 1) s += __shfl_down(s, off, 64);
    __shared__ float red[4];
    if ((threadIdx.x & 63) == 0) red[threadIdx.x >> 6] = s;
    __syncthreads();
    if (threadIdx.x == 0) atomicAdd(sumsq, red[0] + red[1] + red[2] + red[3]);
}

// Fallback reduce for small-ws atomic-replica modes.
__global__ __launch_bounds__(256) void sig_reduce_kernel(
    const float* __restrict__ ws, int nrows, float* __restrict__ sumsq)
{
    const int d = blockIdx.x * 256 + threadIdx.x;
    float s = 0.0f;
    if (d < DTOT) {
        for (int r = 0; r < nrows; ++r) s += ws[(size_t)r * DTOT + d];
        s = s * s;
    }
    for (int off = 32; off > 0; off >>= 1) s += __shfl_down(s, off, 64);
    __shared__ float red[4];
    if ((threadIdx.x & 63) == 0) red[threadIdx.x >> 6] = s;
    __syncthreads();
    if (threadIdx.x == 0) atomicAdd(sumsq, red[0] + red[1] + red[2] + red[3]);
}

__global__ void sig_norm_kernel(const float* __restrict__ sumsq, float* __restrict__ out)
{
    if (threadIdx.x == 0) out[0] = sqrtf(sumsq[0]) * (1.0f / (float)BSZ);
}

extern "C" void kernel_launch(void* const* d_in, const int* in_sizes, int n_in,
                              void* d_out, int out_size, void* d_ws, size_t ws_size,
                              hipStream_t stream) {
    const float* original   = (const float*)d_in[0];
    const float* generated  = (const float*)d_in[1];
    const int*   sample_idx = (const int*)d_in[2];
    float* out = (float*)d_out;
    float* ws  = (float*)d_ws;

    const size_t need_store = ((size_t)(NBLK + 1) * DTOT + 1) * sizeof(float);

    if (ws_size >= need_store) {
        float* accvec = ws + (size_t)NBLK * DTOT;
        float* sumsq  = accvec + DTOT;
        hipMemsetAsync(accvec, 0, (DTOT + 1) * sizeof(float), stream);
        sig_accum_kernel<<<NBLK, 128, 0, stream>>>(original, generated, sample_idx,
                                                   ws, 1, 1);
        dim3 g1((DTOT / 2 + 255) / 256, 64);
        sig_sum_kernel<<<g1, 256, 0, stream>>>(ws, accvec);
        sig_sumsq_kernel<<<(DTOT + 255) / 256, 256, 0, stream>>>(accvec, sumsq);
        sig_norm_kernel<<<1, 64, 0, stream>>>(sumsq, out);
    } else {
        int nrep = 1;
        if (ws_size >= ((size_t)64 * DTOT + 1) * sizeof(float)) nrep = 64;
        else if (ws_size >= ((size_t)8 * DTOT + 1) * sizeof(float)) nrep = 8;
        float* sumsq = ws + (size_t)nrep * DTOT;
        hipMemsetAsync(ws, 0, ((size_t)nrep * DTOT + 1) * sizeof(float), stream);
        sig_accum_kernel<<<NBLK, 128, 0, stream>>>(original, generated, sample_idx,
                                                   ws, nrep, 0);
        sig_reduce_kernel<<<(DTOT + 255) / 256, 256, 0, stream>>>(ws, nrep, sumsq);
        sig_norm_kernel<<<1, 64, 0, stream>>>(sumsq, out);
    }
}

// Round 6
// 299.049 us; speedup vs baseline: 4.1854x; 1.0337x over previous
//
#include <hip/hip_runtime.h>

// SigWassersteinMetric: depth-4 path signature, C=10, T=256.
//   original: (4096, 256, 10) f32; generated: (1024, 256, 10) f32; sample_idx: (1024,)
// 2048 blocks (1024 sampled originals + 1024 generated), 128 threads each.
//
// Horner-factored Chen step (verified rounds 2/4/5):
//   A2 = S2 + (S1 + v/4) (x) v/3
//   B2 = S2 + (S1 + v/3) (x) v/2
//   A3 = S3 + A2 (x) v/2 ;  S4' = S4 + A3 (x) v ;  S3' = S3 + B2 (x) v
//   S2' = S2 + (S1 + v/2) (x) v ;  S1' = S1 + v
//
// Barrier-free main loop (round 5) + register-budget fixes (round 6):
//  - level-1 is CLOSED FORM (S1[c] = x[T-1][c] - x[0][c]) -> epilogue only.
//  - q-interleaved level-2/3/4 so a2/b2 are scalars, not arrays.
// Thread t (<125) owns transposed rows m' = {4t..4t+3, 500+4t..500+4t+3}
// (ij0 = 4t%100, k0 = 4t/100; 4 ij values x 2 k values), and replicates the
// S1/S2 components it needs in registers (s1a,s1b,s2[4]).
// Target: <=128 VGPRs so __launch_bounds__(128,4) holds without AGPR/scratch
// spill (round 5: VGPR_Count=64 + 32MB scratch writes = 2.2x VALU inflation).
#define T_LEN 256
#define C_DIM 10
#define NSTEP 255
#define BSZ   1024
#define NBLK  2048
#define D1 10
#define D2 100
#define D3 1000
#define DTOT 11110
#define PATH_ELEMS (T_LEN * C_DIM)   // 2560
#define DX_ELEMS (NSTEP * C_DIM)     // 2550
#define DXROW 12                     // padded dx row stride (48 B, 16B-aligned)

__global__ __launch_bounds__(128, 4) void sig_accum_kernel(
    const float* __restrict__ original,
    const float* __restrict__ generated,
    const int* __restrict__ sample_idx,
    float* __restrict__ ws, int nrep, int store_mode)
{
    const int tid = threadIdx.x;
    const int b   = blockIdx.x;

    __shared__ float s_dx[NSTEP * DXROW];  // 12240 B (only LDS use)

    const float* path;
    float sign;
    if (b < BSZ) { path = original + (size_t)sample_idx[b] * PATH_ELEMS; sign = 1.0f; }
    else         { path = generated + (size_t)(b - BSZ) * PATH_ELEMS;    sign = -1.0f; }

    for (int idx = tid; idx < DX_ELEMS; idx += 128) {
        int t = idx / C_DIM, c = idx - t * C_DIM;
        s_dx[t * DXROW + c] = path[idx + C_DIM] - path[idx];
    }
    __syncthreads();   // the ONLY barrier

    const int m0  = 4 * tid;                 // valid tid<125
    const int k0  = m0 / 100;                // 0..4
    const int ij0 = m0 - k0 * 100;           // 0,4,...,96
    const int ia  = ij0 / 10;                // i for q0,q1
    const int ib  = (ij0 + 2) / 10;          // i for q2,q3
    const int j0  = ij0 - ia * 10;           // even
    const int jc  = (j0 + 2) % 10;           // even

    float s1a = 0.0f, s1b = 0.0f;
    float s2[4] = {0.0f, 0.0f, 0.0f, 0.0f};
    float s3[8];
    float acc[8][10];                        // rows 0-3: k0; rows 4-7: k0+5
    #pragma unroll
    for (int r = 0; r < 8; ++r) {
        s3[r] = 0.0f;
        #pragma unroll
        for (int l = 0; l < 10; ++l) acc[r][l] = 0.0f;
    }

    if (tid < 125) {
        const float* vrow = s_dx;
        #pragma unroll 1
        for (int t = 0; t < NSTEP; ++t, vrow += DXROW) {
            // ---- LDS loads (read-only, fixed per-thread offsets) ----
            const float4 va = *(const float4*)(vrow);       // v0..v3
            const float4 vb = *(const float4*)(vrow + 4);   // v4..v7
            const float2 vc = *(const float2*)(vrow + 8);   // v8,v9
            const float2 vjA = *(const float2*)(vrow + j0); // vj q0,q1 (8B aligned)
            const float2 vjB = *(const float2*)(vrow + jc); // vj q2,q3 (8B aligned)
            const float via = vrow[ia];
            const float vib = vrow[ib];
            const float vk0 = vrow[k0];
            const float vk1 = vrow[k0 + 5];

            const float vv[10] = {va.x, va.y, va.z, va.w,
                                  vb.x, vb.y, vb.z, vb.w, vc.x, vc.y};
            const float vj[4] = {vjA.x, vjA.y, vjB.x, vjB.y};
            const float vk0h = vk0 * 0.5f;
            const float vk1h = vk1 * 0.5f;

            // ---- q-interleaved level-2/3/4, all registers ----
            #pragma unroll
            for (int q = 0; q < 4; ++q) {
                const float s1q = (q < 2) ? s1a : s1b;
                const float viq = (q < 2) ? via : vib;
                const float a2q = s2[q] + (s1q + viq * 0.25f)        * (vj[q] * (1.0f / 3.0f));
                const float b2q = s2[q] + (s1q + viq * (1.0f/3.0f))  * (vj[q] * 0.5f);
                s2[q]           = s2[q] + (s1q + viq * 0.5f)         * vj[q];

                const float a3x = s3[q] + a2q * vk0h;
                s3[q] += b2q * vk0;
                #pragma unroll
                for (int l = 0; l < 10; ++l) acc[q][l] += a3x * vv[l];

                const float a3y = s3[4 + q] + a2q * vk1h;
                s3[4 + q] += b2q * vk1;
                #pragma unroll
                for (int l = 0; l < 10; ++l) acc[4 + q][l] += a3y * vv[l];
            }
            s1a += via;
            s1b += vib;
        }
    }

    // ---- Epilogue ----
    // Level-1 closed form: S1[c] = x[T-1][c] - x[0][c] (two global reads).
    // S2 replicas agree across k0 groups; threads 0..24 (ij0 = 4*tid) write them.
    if (store_mode) {
        float* orow = ws + (size_t)b * DTOT;
        if (tid < D1) orow[tid] = sign * (path[(T_LEN - 1) * C_DIM + tid] - path[tid]);
        if (tid < 25) {
            #pragma unroll
            for (int q = 0; q < 4; ++q) orow[D1 + ij0 + q] = sign * s2[q];
        }
        if (tid < 125) {
            #pragma unroll
            for (int ch = 0; ch < 2; ++ch) {
                const int kk = k0 + 5 * ch;
                #pragma unroll
                for (int r = 0; r < 4; ++r) {
                    const int idx3 = (ij0 + r) * 10 + kk;
                    orow[D1 + D2 + idx3] = sign * s3[ch * 4 + r];
                    float* p4 = orow + D1 + D2 + D3 + (size_t)idx3 * 10;
                    #pragma unroll
                    for (int l = 0; l < 10; l += 2)
                        *(float2*)&p4[l] = make_float2(sign * acc[ch * 4 + r][l],
                                                       sign * acc[ch * 4 + r][l + 1]);
                }
            }
        }
    } else {
        float* base = ws + (size_t)(b % nrep) * DTOT;
        if (tid < D1)
            atomicAdd(&base[tid], sign * (path[(T_LEN - 1) * C_DIM + tid] - path[tid]));
        if (tid < 25) {
            #pragma unroll
            for (int q = 0; q < 4; ++q) atomicAdd(&base[D1 + ij0 + q], sign * s2[q]);
        }
        if (tid < 125) {
            #pragma unroll
            for (int ch = 0; ch < 2; ++ch) {
                const int kk = k0 + 5 * ch;
                #pragma unroll
                for (int r = 0; r < 4; ++r) {
                    const int idx3 = (ij0 + r) * 10 + kk;
                    atomicAdd(&base[D1 + D2 + idx3], sign * s3[ch * 4 + r]);
                    #pragma unroll
                    for (int l = 0; l < 10; ++l)
                        atomicAdd(&base[D1 + D2 + D3 + idx3 * 10 + l],
                                  sign * acc[ch * 4 + r][l]);
                }
            }
        }
    }
}

// Stage 1: block sums 32 rows for a 512-float d-tile (float2 lanes, coalesced),
// atomically accumulates into accvec[DTOT]. Grid: (ceil(5555/256), 64).
__global__ __launch_bounds__(256) void sig_sum_kernel(
    const float* __restrict__ ws, float* __restrict__ accvec)
{
    const int d2 = blockIdx.x * 256 + threadIdx.x;   // float2 index, DTOT/2 = 5555
    if (d2 >= DTOT / 2) return;
    const float* p = ws + (size_t)(blockIdx.y * 32) * DTOT + 2 * d2;
    float sx = 0.0f, sy = 0.0f;
    #pragma unroll
    for (int r = 0; r < 32; ++r) {
        const float2 v = *(const float2*)(p + (size_t)r * DTOT);
        sx += v.x; sy += v.y;
    }
    atomicAdd(&accvec[2 * d2], sx);
    atomicAdd(&accvec[2 * d2 + 1], sy);
}

// Stage 2: sum of squares of accvec -> atomicAdd(sumsq).
__global__ __launch_bounds__(256) void sig_sumsq_kernel(
    const float* __restrict__ accvec, float* __restrict__ sumsq)
{
    const int d = blockIdx.x * 256 + threadIdx.x;
    float s = 0.0f;
    if (d < DTOT) { float v = accvec[d]; s = v * v; }
    for (int off = 32; off > 0; off >>= 1) s += __shfl_down(s, off, 64);
    __shared__ float red[4];
    if ((threadIdx.x & 63) == 0) red[threadIdx.x >> 6] = s;
    __syncthreads();
    if (threadIdx.x == 0) atomicAdd(sumsq, red[0] + red[1] + red[2] + red[3]);
}

// Fallback reduce for small-ws atomic-replica modes.
__global__ __launch_bounds__(256) void sig_reduce_kernel(
    const float* __restrict__ ws, int nrows, float* __restrict__ sumsq)
{
    const int d = blockIdx.x * 256 + threadIdx.x;
    float s = 0.0f;
    if (d < DTOT) {
        for (int r = 0; r < nrows; ++r) s += ws[(size_t)r * DTOT + d];
        s = s * s;
    }
    for (int off = 32; off > 0; off >>= 1) s += __shfl_down(s, off, 64);
    __shared__ float red[4];
    if ((threadIdx.x & 63) == 0) red[threadIdx.x >> 6] = s;
    __syncthreads();
    if (threadIdx.x == 0) atomicAdd(sumsq, red[0] + red[1] + red[2] + red[3]);
}

__global__ void sig_norm_kernel(const float* __restrict__ sumsq, float* __restrict__ out)
{
    if (threadIdx.x == 0) out[0] = sqrtf(sumsq[0]) * (1.0f / (float)BSZ);
}

extern "C" void kernel_launch(void* const* d_in, const int* in_sizes, int n_in,
                              void* d_out, int out_size, void* d_ws, size_t ws_size,
                              hipStream_t stream) {
    const float* original   = (const float*)d_in[0];
    const float* generated  = (const float*)d_in[1];
    const int*   sample_idx = (const int*)d_in[2];
    float* out = (float*)d_out;
    float* ws  = (float*)d_ws;

    const size_t need_store = ((size_t)(NBLK + 1) * DTOT + 1) * sizeof(float);

    if (ws_size >= need_store) {
        float* accvec = ws + (size_t)NBLK * DTOT;
        float* sumsq  = accvec + DTOT;
        hipMemsetAsync(accvec, 0, (DTOT + 1) * sizeof(float), stream);
        sig_accum_kernel<<<NBLK, 128, 0, stream>>>(original, generated, sample_idx,
                                                   ws, 1, 1);
        dim3 g1((DTOT / 2 + 255) / 256, 64);
        sig_sum_kernel<<<g1, 256, 0, stream>>>(ws, accvec);
        sig_sumsq_kernel<<<(DTOT + 255) / 256, 256, 0, stream>>>(accvec, sumsq);
        sig_norm_kernel<<<1, 64, 0, stream>>>(sumsq, out);
    } else {
        int nrep = 1;
        if (ws_size >= ((size_t)64 * DTOT + 1) * sizeof(float)) nrep = 64;
        else if (ws_size >= ((size_t)8 * DTOT + 1) * sizeof(float)) nrep = 8;
        float* sumsq = ws + (size_t)nrep * DTOT;
        hipMemsetAsync(ws, 0, ((size_t)nrep * DTOT + 1) * sizeof(float), stream);
        sig_accum_kernel<<<NBLK, 128, 0, stream>>>(original, generated, sample_idx,
                                                   ws, nrep, 0);
        sig_reduce_kernel<<<(DTOT + 255) / 256, 256, 0, stream>>>(ws, nrep, sumsq);
        sig_norm_kernel<<<1, 64, 0, stream>>>(sumsq, out);
    }
}